// Round 7
// baseline (230.227 us; speedup 1.0000x reference)
//
#include <hip/hip_runtime.h>

#define T_MAX 512
#define BATCH 32
#define CLASSES 1296
#define L_MAX 64
#define NROWS (T_MAX * BATCH)   // 16384
#define NV4 (CLASSES / 4)       // 324
#define NINF (-INFINITY)

// DPP wave64 sum: row_shr 1/2/4/8 + row_bcast 15/31. Total lands in LANE 63.
__device__ __forceinline__ float wave_sum64(float v) {
    v += __int_as_float(__builtin_amdgcn_update_dpp(0, __float_as_int(v), 0x111, 0xF, 0xF, true));
    v += __int_as_float(__builtin_amdgcn_update_dpp(0, __float_as_int(v), 0x112, 0xF, 0xF, true));
    v += __int_as_float(__builtin_amdgcn_update_dpp(0, __float_as_int(v), 0x114, 0xF, 0xF, true));
    v += __int_as_float(__builtin_amdgcn_update_dpp(0, __float_as_int(v), 0x118, 0xF, 0xF, true));
    v += __int_as_float(__builtin_amdgcn_update_dpp(0, __float_as_int(v), 0x142, 0xF, 0xF, true));
    v += __int_as_float(__builtin_amdgcn_update_dpp(0, __float_as_int(v), 0x143, 0xF, 0xF, true));
    return v;
}

// async global->LDS, 16 B per lane. Dest is wave-uniform base + lane*16.
__device__ __forceinline__ void glds16(const float* g, float* l) {
    __builtin_amdgcn_global_load_lds((const __attribute__((address_space(1))) void*)g,
                                     (__attribute__((address_space(3))) void*)l, 16, 0, 0);
}

// ---------------------------------------------------------------------------
// K1 (R5 version, at the ~2.7 TB/s env wall): wave per (pred,seq) row pair,
// register loads, DPP reduce, pb gather. Also zero-inits acc+counter.
// ---------------------------------------------------------------------------
__global__ __launch_bounds__(256) void rowstats_kernel(
    const float* __restrict__ pred, const float* __restrict__ seqp,
    const int* __restrict__ label,
    float* __restrict__ lse_pred, float* __restrict__ sum_pred,
    float* __restrict__ lse_seq, float* __restrict__ pb,
    int* __restrict__ counter, float* __restrict__ acc)
{
    int r = blockIdx.x * 4 + (threadIdx.x >> 6);   // row in [0, NROWS)
    int lane = threadIdx.x & 63;
    if (r == 0 && lane == 0) { *counter = 0; *acc = 0.f; }
    const float* xp = pred + (size_t)r * CLASSES;
    const float* xs = seqp + (size_t)r * CLASSES;
    const float4* p4 = (const float4*)xp;
    const float4* s4 = (const float4*)xs;

    float4 a0 = p4[lane],       a1 = p4[lane + 64],  a2 = p4[lane + 128];
    float4 a3 = p4[lane + 192], a4 = p4[lane + 256];
    float4 b0 = s4[lane],       b1 = s4[lane + 64],  b2 = s4[lane + 128];
    float4 b3 = s4[lane + 192], b4 = s4[lane + 256];
    float4 at = make_float4(0.f, 0.f, 0.f, 0.f);
    float4 bt = make_float4(0.f, 0.f, 0.f, 0.f);
    if (lane < 4) { at = p4[320 + lane]; bt = s4[320 + lane]; }
    int lab = label[((r & 31) << 6) + lane];

    float sp = __expf(a0.x) + __expf(a0.y) + __expf(a0.z) + __expf(a0.w)
             + __expf(a1.x) + __expf(a1.y) + __expf(a1.z) + __expf(a1.w)
             + __expf(a2.x) + __expf(a2.y) + __expf(a2.z) + __expf(a2.w)
             + __expf(a3.x) + __expf(a3.y) + __expf(a3.z) + __expf(a3.w)
             + __expf(a4.x) + __expf(a4.y) + __expf(a4.z) + __expf(a4.w);
    float sx = (a0.x + a0.y + a0.z + a0.w) + (a1.x + a1.y + a1.z + a1.w)
             + (a2.x + a2.y + a2.z + a2.w) + (a3.x + a3.y + a3.z + a3.w)
             + (a4.x + a4.y + a4.z + a4.w);
    float ss = __expf(b0.x) + __expf(b0.y) + __expf(b0.z) + __expf(b0.w)
             + __expf(b1.x) + __expf(b1.y) + __expf(b1.z) + __expf(b1.w)
             + __expf(b2.x) + __expf(b2.y) + __expf(b2.z) + __expf(b2.w)
             + __expf(b3.x) + __expf(b3.y) + __expf(b3.z) + __expf(b3.w)
             + __expf(b4.x) + __expf(b4.y) + __expf(b4.z) + __expf(b4.w);
    if (lane < 4) {
        sp += __expf(at.x) + __expf(at.y) + __expf(at.z) + __expf(at.w);
        sx += at.x + at.y + at.z + at.w;
        ss += __expf(bt.x) + __expf(bt.y) + __expf(bt.z) + __expf(bt.w);
    }
    sp = wave_sum64(sp);
    sx = wave_sum64(sx);
    ss = wave_sum64(ss);

    int b = r & 31, t = r >> 5;
    pb[(((size_t)(b << 9) + t) << 6) + lane] = xs[lab];   // seq row is L1-warm
    if (lane == 63) {
        lse_pred[r] = __logf(sp);
        sum_pred[r] = sx;
        lse_seq[r]  = __logf(ss);
    }
}

// ---------------------------------------------------------------------------
// K2 v4: DP alignment + fused CE + final reduce. ONE wave per block (32
// blocks). Panels staged by global_load_lds double-buffer, gated with
// s_waitcnt vmcnt(16) -- no barriers, no producer wave. R-mask folded into a
// bias add off the critical chain. Backtrack via per-row highest-bit jumps,
// parallel interval fill, then CE for this batch with all loads in flight.
// ---------------------------------------------------------------------------
__global__ __launch_bounds__(64) void align_ce_kernel(
    const float* __restrict__ pb, const float* __restrict__ pred,
    const int* __restrict__ label, const int* __restrict__ x_len,
    const int* __restrict__ label_len,
    const float* __restrict__ lse_pred, const float* __restrict__ sum_pred,
    const float* __restrict__ lse_seq,
    float* __restrict__ acc, int* __restrict__ counter, float* __restrict__ out)
{
    int b = blockIdx.x, lane = threadIdx.x;
    int C = x_len[b], R = label_len[b];
    int limit = C - R;
    __shared__ float buf[2][4096];       // two 64-col panels (32 KB)
    __shared__ uint2 chw[512];           // per-panel per-lane choice bits (4 KB)
    __shared__ int labs[64];
    __shared__ int a_s[64];              // interval start per row
    __shared__ int rows_s[T_MAX];
    const float* pbb = pb + ((size_t)b << 15);   // b * 512 * 64
    int P = (C + 63) >> 6;

    labs[lane] = label[(b << 6) + lane];
    float biasR = (lane < R) ? 0.f : NINF;
    bool isb0 = (lane & 15) == 0;
    const int ninf_i = 0xFF800000;

    // prologue: stage panel 0 (16 KB, 16 async 1-KB chunks)
    #pragma unroll
    for (int k = 0; k < 16; ++k) glds16(pbb + (k << 8) + lane * 4, &buf[0][k << 8]);

    float dp = NINF;
    for (int p = 0; p < P; ++p) {
        // issue next panel into the other buffer (clamped source)
        int ldp = p + 1; if (ldp >= P) ldp = P - 1;
        const float* src = pbb + ((size_t)ldp << 12);
        float* dst = buf[(p + 1) & 1];
        #pragma unroll
        for (int k = 0; k < 16; ++k) glds16(src + (k << 8) + lane * 4, &dst[k << 8]);
        __asm__ __volatile__("s_waitcnt vmcnt(16)" ::: "memory");  // panel p landed

        const float* bc = buf[p & 1];
        int base = p << 6;
        unsigned w0 = 0, w1 = 0;
        #pragma unroll
        for (int g = 0; g < 4; ++g) {
            float v[16];
            #pragma unroll
            for (int u = 0; u < 16; ++u) v[u] = bc[((g << 4) + u) * 64 + lane];
            bool general = (p == 0) || (base + (g << 4) + 15 > limit);
            #pragma unroll
            for (int u = 0; u < 16; ++u) {
                int kk = (g << 4) + u;
                int j = base + kk;
                float val;
                if (general) {
                    if (p == 0 && kk == 0) {            // column 0 init
                        dp = (lane == 0) ? v[0] : NINF;
                        continue;
                    }
                    bool ib = (lane <= j) && (lane >= j - limit) && (lane < R);
                    val = ib ? v[u] : NINF;
                } else {
                    val = v[u] + biasR;                  // off-chain R mask
                }
                int dpb = __float_as_int(dp);
                int t1 = __builtin_amdgcn_update_dpp(ninf_i, dpb, 0x111, 0xF, 0xF, false); // row_shr:1
                int t2 = __builtin_amdgcn_update_dpp(ninf_i, dpb, 0x142, 0xF, 0xF, false); // row_bcast15
                float shifted = __int_as_float(isb0 ? t2 : t1);
                bool c = shifted > dp;                   // strict (off critical chain)
                unsigned bit01 = c ? 1u : 0u;
                if (kk < 32) w0 |= bit01 << kk; else w1 |= bit01 << (kk - 32);
                dp = fmaxf(shifted, dp) + val;           // == reference select
            }
        }
        chw[(p << 6) + lane] = make_uint2(w0, w1);
    }
    __asm__ __volatile__("s_waitcnt vmcnt(0)" ::: "memory");

    // backtrack: per-row jumps via highest set bit in cached 32-bit words
    if (lane == 0) {
        const unsigned* ch32 = (const unsigned*)chw;
        int row = R - 1, j = C - 1;
        while (row > 0 && j >= 0) {
            unsigned word = ch32[((j >> 6) << 7) + (row << 1) + ((j >> 5) & 1)];
            unsigned mb = (2u << (j & 31)) - 1;
            unsigned m = word & mb;
            if (m) {
                int hb = 31 - __clz(m);
                int aj = (j & ~31) | hb;
                a_s[row] = aj;
                row--; j = aj - 1;
            } else {
                j = (j & ~31) - 1;
            }
        }
        for (int i = row; i >= 0; --i) a_s[i] = 0;
    }
    // parallel interval fill: row i occupies [a_s[i], b_i]
    if (lane < R) {
        int a = a_s[lane];
        int bi = (lane == R - 1) ? (C - 1) : (a_s[lane + 1] - 1);
        for (int j = a; j <= bi; ++j) rows_s[j] = lane;
    }

    // ---- fused CE for batch b: elements e = t*32 + b ----
    int row8[8], tgt8[8];
    float pv[8], pbv[8], lp8[8], sx8[8], lsq8[8];
    #pragma unroll
    for (int it = 0; it < 8; ++it) {
        int t = (it << 6) + lane;
        row8[it] = (t < C) ? rows_s[t] : 0;
    }
    #pragma unroll
    for (int it = 0; it < 8; ++it) tgt8[it] = labs[row8[it]];
    #pragma unroll
    for (int it = 0; it < 8; ++it) {                    // all loads in flight
        int t = (it << 6) + lane;
        int e = (t << 5) + b;
        pv[it]  = pred[(size_t)e * CLASSES + tgt8[it]];
        pbv[it] = pb[(((size_t)(b << 9) + t) << 6) + row8[it]];
        lp8[it] = lse_pred[e];
        sx8[it] = sum_pred[e];
        lsq8[it] = lse_seq[e];
    }
    float ces = 0.f;
    #pragma unroll
    for (int it = 0; it < 8; ++it) {
        int t = (it << 6) + lane;
        if (t < C) {
            float lp = lp8[it];
            float S = sx8[it] - (float)CLASSES * lp;    // sum_v log_softmax(pred)
            float lsp_t = pv[it] - lp;
            float conf = __expf(pbv[it] - lsq8[it]);
            float smooth = (1.f - conf) * (1.f / (float)(CLASSES - 1));
            ces += -((conf - smooth) * lsp_t + smooth * S);
        }
    }
    ces = wave_sum64(ces);                              // total in lane 63
    if (lane == 63) {
        __hip_atomic_fetch_add(acc, ces, __ATOMIC_ACQ_REL, __HIP_MEMORY_SCOPE_AGENT);
        int c = __hip_atomic_fetch_add(counter, 1, __ATOMIC_ACQ_REL, __HIP_MEMORY_SCOPE_AGENT);
        if (c == BATCH - 1) {
            float tot = __hip_atomic_load(acc, __ATOMIC_ACQUIRE, __HIP_MEMORY_SCOPE_AGENT);
            out[0] = tot * (1.0f / (float)NROWS);
        }
    }
}

extern "C" void kernel_launch(void* const* d_in, const int* in_sizes, int n_in,
                              void* d_out, int out_size, void* d_ws, size_t ws_size,
                              hipStream_t stream) {
    const float* pred      = (const float*)d_in[0];
    const float* seq_pred  = (const float*)d_in[1];
    const int*   label     = (const int*)d_in[2];
    const int*   x_len     = (const int*)d_in[3];
    const int*   label_len = (const int*)d_in[4];
    float* out = (float*)d_out;

    // workspace layout (floats)
    float* w = (float*)d_ws;
    float* lse_pred = w;                       // 16384
    float* sum_pred = w + NROWS;               // 16384
    float* lse_seq  = w + 2 * NROWS;           // 16384
    float* pb       = w + 3 * NROWS;           // 32*512*64 = 1048576
    float* acc      = w + 3 * NROWS + (size_t)BATCH * T_MAX * 64;  // 1
    int*   counter  = (int*)(acc + 1);         // 1

    rowstats_kernel<<<NROWS / 4, 256, 0, stream>>>(pred, seq_pred, label,
                                                   lse_pred, sum_pred, lse_seq, pb,
                                                   counter, acc);
    align_ce_kernel<<<BATCH, 64, 0, stream>>>(pb, pred, label, x_len, label_len,
                                              lse_pred, sum_pred, lse_seq,
                                              acc, counter, out);
}

// Round 8
// 219.412 us; speedup vs baseline: 1.0493x; 1.0493x over previous
//
#include <hip/hip_runtime.h>

#define T_MAX 512
#define BATCH 32
#define CLASSES 1296
#define L_MAX 64
#define NROWS (T_MAX * BATCH)   // 16384
#define NV4 (CLASSES / 4)       // 324
#define NINF (-INFINITY)

// DPP wave64 sum: row_shr 1/2/4/8 + row_bcast 15/31. Total lands in LANE 63.
__device__ __forceinline__ float wave_sum64(float v) {
    v += __int_as_float(__builtin_amdgcn_update_dpp(0, __float_as_int(v), 0x111, 0xF, 0xF, true));
    v += __int_as_float(__builtin_amdgcn_update_dpp(0, __float_as_int(v), 0x112, 0xF, 0xF, true));
    v += __int_as_float(__builtin_amdgcn_update_dpp(0, __float_as_int(v), 0x114, 0xF, 0xF, true));
    v += __int_as_float(__builtin_amdgcn_update_dpp(0, __float_as_int(v), 0x118, 0xF, 0xF, true));
    v += __int_as_float(__builtin_amdgcn_update_dpp(0, __float_as_int(v), 0x142, 0xF, 0xF, true));
    v += __int_as_float(__builtin_amdgcn_update_dpp(0, __float_as_int(v), 0x143, 0xF, 0xF, true));
    return v;
}

// async global->LDS, 16 B per lane. Dest is wave-uniform base + lane*16.
__device__ __forceinline__ void glds16(const float* g, float* l) {
    __builtin_amdgcn_global_load_lds((const __attribute__((address_space(1))) void*)g,
                                     (__attribute__((address_space(3))) void*)l, 16, 0, 0);
}

// ---------------------------------------------------------------------------
// K1: seq_pred half of rowstats. One wave per seq row: exp-sum (no max, N(0,1)
// safe), DPP reduce, pb gather from the L1-warm row. Inits ce's counter.
// ---------------------------------------------------------------------------
__global__ __launch_bounds__(256) void seq_rowstats_kernel(
    const float* __restrict__ seqp, const int* __restrict__ label,
    float* __restrict__ lse_seq, float* __restrict__ pb, int* __restrict__ counter)
{
    int r = blockIdx.x * 4 + (threadIdx.x >> 6);   // seq row in [0, NROWS)
    int lane = threadIdx.x & 63;
    if (r == 0 && lane == 0) *counter = 0;
    const float* xs = seqp + (size_t)r * CLASSES;
    const float4* s4 = (const float4*)xs;

    float4 b0 = s4[lane],       b1 = s4[lane + 64],  b2 = s4[lane + 128];
    float4 b3 = s4[lane + 192], b4 = s4[lane + 256];
    float4 bt = make_float4(0.f, 0.f, 0.f, 0.f);
    if (lane < 4) bt = s4[320 + lane];
    int lab = label[((r & 31) << 6) + lane];

    float ss = __expf(b0.x) + __expf(b0.y) + __expf(b0.z) + __expf(b0.w)
             + __expf(b1.x) + __expf(b1.y) + __expf(b1.z) + __expf(b1.w)
             + __expf(b2.x) + __expf(b2.y) + __expf(b2.z) + __expf(b2.w)
             + __expf(b3.x) + __expf(b3.y) + __expf(b3.z) + __expf(b3.w)
             + __expf(b4.x) + __expf(b4.y) + __expf(b4.z) + __expf(b4.w);
    if (lane < 4)
        ss += __expf(bt.x) + __expf(bt.y) + __expf(bt.z) + __expf(bt.w);
    ss = wave_sum64(ss);

    int b = r & 31, t = r >> 5;
    pb[(((size_t)(b << 9) + t) << 6) + lane] = xs[lab];   // row is L1-warm
    if (lane == 63) lse_seq[r] = __logf(ss);
}

// ---------------------------------------------------------------------------
// K2: FUSED. Blocks 0..31 = align DP (single wave, glds 32-col double buffer,
// DPP chain, bit-jump backtrack). Blocks 32.. = pred rowstats (streaming).
// The 4096 pred blocks keep all CUs busy (and clocks high) while the 32
// serial DP waves run concurrently -- align's latency hides under them.
// ---------------------------------------------------------------------------
__global__ __launch_bounds__(256) void fused_align_pred_kernel(
    const float* __restrict__ pred, const float* __restrict__ pb,
    const int* __restrict__ x_len, const int* __restrict__ label_len,
    float* __restrict__ lse_pred, float* __restrict__ sum_pred,
    int* __restrict__ tg)
{
    __shared__ float abuf[2][2048];      // two 32-col panels (16 KB)
    __shared__ unsigned chw[1024];       // [panel 0..15][lane] choice bits (4 KB)
    __shared__ int a_s[64];
    __shared__ int rows_s[T_MAX];

    if (blockIdx.x < 32) {
        // ---------------- align path: one wave ----------------
        if (threadIdx.x >= 64) return;
        int b = blockIdx.x, lane = threadIdx.x;
        int C = x_len[b], R = label_len[b];
        int limit = C - R;
        const float* pbb = pb + ((size_t)b << 15);   // b * 512 * 64
        int P = (C + 31) >> 5;

        float biasR = (lane < R) ? 0.f : NINF;
        bool isb0 = (lane & 15) == 0;
        const int ninf_i = 0xFF800000;

        // prologue: stage panel 0 (8 KB = 8 async 1-KB chunks)
        #pragma unroll
        for (int k = 0; k < 8; ++k) glds16(pbb + (k << 8) + lane * 4, &abuf[0][k << 8]);

        float dp = NINF;
        for (int p = 0; p < P; ++p) {
            int ldp = p + 1; if (ldp >= P) ldp = P - 1;
            const float* src = pbb + ((size_t)ldp << 11);
            float* dst = abuf[(p + 1) & 1];
            #pragma unroll
            for (int k = 0; k < 8; ++k) glds16(src + (k << 8) + lane * 4, &dst[k << 8]);
            __asm__ __volatile__("s_waitcnt vmcnt(8)" ::: "memory");  // panel p landed

            const float* bc = abuf[p & 1];
            int base = p << 5;
            unsigned w0 = 0;
            #pragma unroll
            for (int g = 0; g < 2; ++g) {
                float v[16];
                #pragma unroll
                for (int u = 0; u < 16; ++u) v[u] = bc[((g << 4) + u) * 64 + lane];
                bool general = (p == 0) || (base + (g << 4) + 15 > limit);
                #pragma unroll
                for (int u = 0; u < 16; ++u) {
                    int kk = (g << 4) + u;
                    int j = base + kk;
                    float val;
                    if (general) {
                        if (p == 0 && kk == 0) {            // column 0 init
                            dp = (lane == 0) ? v[0] : NINF;
                            continue;
                        }
                        bool ib = (lane <= j) && (lane >= j - limit) && (lane < R);
                        val = ib ? v[u] : NINF;
                    } else {
                        val = v[u] + biasR;                  // off-chain R mask
                    }
                    int dpb = __float_as_int(dp);
                    int t1 = __builtin_amdgcn_update_dpp(ninf_i, dpb, 0x111, 0xF, 0xF, false); // row_shr:1
                    int t2 = __builtin_amdgcn_update_dpp(ninf_i, dpb, 0x142, 0xF, 0xF, false); // row_bcast15
                    float shifted = __int_as_float(isb0 ? t2 : t1);
                    bool c = shifted > dp;                   // strict (off critical chain)
                    w0 |= (c ? 1u : 0u) << kk;
                    dp = fmaxf(shifted, dp) + val;           // == reference select
                }
            }
            chw[(p << 6) + lane] = w0;
        }
        __asm__ __volatile__("s_waitcnt vmcnt(0)" ::: "memory");

        // backtrack: per-row jumps via highest set bit in cached words
        if (lane == 0) {
            int row = R - 1, j = C - 1;
            while (row > 0 && j >= 0) {
                unsigned word = chw[((j >> 5) << 6) + row];
                unsigned mb = (2u << (j & 31)) - 1;
                unsigned m = word & mb;
                if (m) {
                    int hb = 31 - __clz(m);
                    int aj = (j & ~31) | hb;
                    a_s[row] = aj;
                    row--; j = aj - 1;
                } else {
                    j = (j & ~31) - 1;
                }
            }
            for (int i = row; i >= 0; --i) a_s[i] = 0;
        }
        // parallel interval fill: row i occupies [a_s[i], b_i]
        if (lane < R) {
            int a = a_s[lane];
            int bi = (lane == R - 1) ? (C - 1) : (a_s[lane + 1] - 1);
            for (int j = a; j <= bi; ++j) rows_s[j] = lane;
        }
        for (int j = lane; j < T_MAX; j += 64)
            tg[(b << 9) + j] = (j < C) ? rows_s[j] : -1;
    } else {
        // ---------------- pred rowstats path: one wave per row ----------------
        int r = (blockIdx.x - 32) * 4 + (threadIdx.x >> 6);   // [0, NROWS)
        int lane = threadIdx.x & 63;
        const float* xp = pred + (size_t)r * CLASSES;
        const float4* p4 = (const float4*)xp;

        float4 a0 = p4[lane],       a1 = p4[lane + 64],  a2 = p4[lane + 128];
        float4 a3 = p4[lane + 192], a4 = p4[lane + 256];
        float4 at = make_float4(0.f, 0.f, 0.f, 0.f);
        if (lane < 4) at = p4[320 + lane];

        float sp = __expf(a0.x) + __expf(a0.y) + __expf(a0.z) + __expf(a0.w)
                 + __expf(a1.x) + __expf(a1.y) + __expf(a1.z) + __expf(a1.w)
                 + __expf(a2.x) + __expf(a2.y) + __expf(a2.z) + __expf(a2.w)
                 + __expf(a3.x) + __expf(a3.y) + __expf(a3.z) + __expf(a3.w)
                 + __expf(a4.x) + __expf(a4.y) + __expf(a4.z) + __expf(a4.w);
        float sx = (a0.x + a0.y + a0.z + a0.w) + (a1.x + a1.y + a1.z + a1.w)
                 + (a2.x + a2.y + a2.z + a2.w) + (a3.x + a3.y + a3.z + a3.w)
                 + (a4.x + a4.y + a4.z + a4.w);
        if (lane < 4) {
            sp += __expf(at.x) + __expf(at.y) + __expf(at.z) + __expf(at.w);
            sx += at.x + at.y + at.z + at.w;
        }
        sp = wave_sum64(sp);
        sx = wave_sum64(sx);
        if (lane == 63) {
            lse_pred[r] = __logf(sp);
            sum_pred[r] = sx;
        }
    }
}

// ---------------------------------------------------------------------------
// K3: per-element CE + fused last-block final reduction (agent-scope atomics).
// ---------------------------------------------------------------------------
__global__ __launch_bounds__(256) void ce_kernel(
    const float* __restrict__ pred, const int* __restrict__ label,
    const int* __restrict__ x_len,
    const float* __restrict__ lse_pred, const float* __restrict__ sum_pred,
    const float* __restrict__ lse_seq, const float* __restrict__ pb,
    const int* __restrict__ tg, float* __restrict__ partials,
    int* __restrict__ counter, float* __restrict__ out)
{
    int e = blockIdx.x * 256 + threadIdx.x;    // e = t*BATCH + b
    int t = e >> 5, b = e & 31;
    float ce = 0.f;
    if (t < x_len[b]) {
        int row = tg[(b << 9) + t];
        int tgt = label[(b << 6) + row];
        float lp = lse_pred[e];
        float S = sum_pred[e] - (float)CLASSES * lp;        // sum_v log_softmax(pred)
        float lsp_t = pred[(size_t)e * CLASSES + tgt] - lp;
        float conf = __expf(pb[(((size_t)(b << 9) + t) << 6) + row] - lse_seq[e]);
        float smooth = (1.f - conf) * (1.f / (float)(CLASSES - 1));
        ce = -((conf - smooth) * lsp_t + smooth * S);
    }
    ce = wave_sum64(ce);                        // total in lane 63
    __shared__ float sm[4];
    __shared__ int amLast;
    if ((threadIdx.x & 63) == 63) sm[threadIdx.x >> 6] = ce;
    __syncthreads();
    if (threadIdx.x == 0) {
        float p = sm[0] + sm[1] + sm[2] + sm[3];
        __hip_atomic_store(&partials[blockIdx.x], p, __ATOMIC_RELEASE, __HIP_MEMORY_SCOPE_AGENT);
        amLast = (__hip_atomic_fetch_add(counter, 1, __ATOMIC_ACQ_REL, __HIP_MEMORY_SCOPE_AGENT) == 63);
    }
    __syncthreads();
    if (amLast && threadIdx.x < 64) {
        float v = __hip_atomic_load(&partials[threadIdx.x], __ATOMIC_ACQUIRE, __HIP_MEMORY_SCOPE_AGENT);
        for (int o = 32; o; o >>= 1) v += __shfl_down(v, o, 64);
        if (threadIdx.x == 0) out[0] = v * (1.0f / (float)NROWS);
    }
}

extern "C" void kernel_launch(void* const* d_in, const int* in_sizes, int n_in,
                              void* d_out, int out_size, void* d_ws, size_t ws_size,
                              hipStream_t stream) {
    const float* pred      = (const float*)d_in[0];
    const float* seq_pred  = (const float*)d_in[1];
    const int*   label     = (const int*)d_in[2];
    const int*   x_len     = (const int*)d_in[3];
    const int*   label_len = (const int*)d_in[4];
    float* out = (float*)d_out;

    // workspace layout (floats)
    float* w = (float*)d_ws;
    float* lse_pred = w;                       // 16384
    float* sum_pred = w + NROWS;               // 16384
    float* lse_seq  = w + 2 * NROWS;           // 16384
    float* pb       = w + 3 * NROWS;           // 32*512*64 = 1048576
    int*   tg       = (int*)(w + 3 * NROWS + (size_t)BATCH * T_MAX * 64); // 16384 ints
    float* partials = (float*)(tg + NROWS);    // 64
    int*   counter  = (int*)(partials + 64);   // 1

    seq_rowstats_kernel<<<NROWS / 4, 256, 0, stream>>>(seq_pred, label,
                                                       lse_seq, pb, counter);
    fused_align_pred_kernel<<<32 + NROWS / 4, 256, 0, stream>>>(pred, pb,
                                                                x_len, label_len,
                                                                lse_pred, sum_pred, tg);
    ce_kernel<<<64, 256, 0, stream>>>(pred, label, x_len,
                                      lse_pred, sum_pred, lse_seq, pb, tg,
                                      partials, counter, out);
}